// Round 1
// 224.656 us; speedup vs baseline: 1.0257x; 1.0257x over previous
//
#include <hip/hip_runtime.h>

// Inverse 2x2 wavelet (Haar-style) reconstruction.
// x: (8, 16, 512, 512) f32, channels [0:4]=lls, [4:8]=hls, [8:12]=lhs, [12:16]=hhs
// out: (8, 4, 1024, 1024) f32
// out[b,c,2i+di,2j+dj] = g0[dj]*(g0[di]*lls + g1[di]*hls) + g1[dj]*(g0[di]*lhs + g1[di]*hhs)
//
// Pure streaming, no reuse. Mapping chosen for FULLY DENSE per-instruction
// coalescing on BOTH sides:
//   - each thread owns 2 input cols -> loads are dwordx2, 8 B/lane,
//     consecutive lanes contiguous (512 B/wave/instruction, dense)
//   - each thread writes 4 output cols per row -> one 16 B store per row,
//     consecutive lanes at 16 B stride (1 KiB/wave/instruction, dense).
// Previous version stored 16 B at a 32 B lane stride: every 128 B line was
// written by two separate NT store instructions (2x L2 write requests +
// partial-line eviction risk with the nt hint).

using f2 = __attribute__((ext_vector_type(2))) float;
using f4 = __attribute__((ext_vector_type(4))) float;

__global__ __launch_bounds__(256) void FreTransferInv_kernel(
    const float* __restrict__ x,
    const float* __restrict__ g0,
    const float* __restrict__ g1,
    float* __restrict__ out)
{
    const float g00 = g0[0], g01 = g0[1];
    const float g10 = g1[0], g11 = g1[1];

    // total threads = 8*4*512*256 = 4,194,304
    const int tid = blockIdx.x * 256 + threadIdx.x;

    const int jg = tid & 255;          // input column pair (2 cols each)
    const int i  = (tid >> 8) & 511;   // input row
    const int bc = tid >> 17;          // b*4 + c, 0..31
    const int b  = bc >> 2;
    const int c  = bc & 3;

    const size_t plane = 512 * 512;
    const size_t in_base =
        ((size_t)(b * 16 + c) * 512 + (size_t)i) * 512 + (size_t)jg * 2;

    const f2 lls = __builtin_nontemporal_load((const f2*)(x + in_base));
    const f2 hls = __builtin_nontemporal_load((const f2*)(x + in_base + 4 * plane));
    const f2 lhs = __builtin_nontemporal_load((const f2*)(x + in_base + 8 * plane));
    const f2 hhs = __builtin_nontemporal_load((const f2*)(x + in_base + 12 * plane));

    f4 ve, vo;  // even output row, odd output row (4 cols each)
#pragma unroll
    for (int k = 0; k < 2; ++k) {
        const float L  = lls[k];
        const float H  = hls[k];
        const float Lh = lhs[k];
        const float Hh = hhs[k];
        const float lo_e = g00 * L  + g10 * H;    // lo at even row
        const float lo_o = g01 * L  + g11 * H;    // lo at odd row
        const float hi_e = g00 * Lh + g10 * Hh;   // hi at even row
        const float hi_o = g01 * Lh + g11 * Hh;   // hi at odd row
        ve[2 * k]     = g00 * lo_e + g10 * hi_e;
        ve[2 * k + 1] = g01 * lo_e + g11 * hi_e;
        vo[2 * k]     = g00 * lo_o + g10 * hi_o;
        vo[2 * k + 1] = g01 * lo_o + g11 * hi_o;
    }

    // output plane stride = 1024*1024; even row = 2i, odd = 2i+1; col base = 4*jg
    const size_t out_e =
        ((size_t)bc * 1024 + (size_t)(2 * i)) * 1024 + (size_t)jg * 4;

    __builtin_nontemporal_store(ve, (f4*)(out + out_e));
    __builtin_nontemporal_store(vo, (f4*)(out + out_e + 1024));
}

extern "C" void kernel_launch(void* const* d_in, const int* in_sizes, int n_in,
                              void* d_out, int out_size, void* d_ws, size_t ws_size,
                              hipStream_t stream) {
    const float* x  = (const float*)d_in[0];
    const float* g0 = (const float*)d_in[1];
    const float* g1 = (const float*)d_in[2];
    float* out = (float*)d_out;

    // 8*4*512*256 threads total / 256 per block
    const int total_threads = 8 * 4 * 512 * 256;
    const int blocks = total_threads / 256;
    FreTransferInv_kernel<<<blocks, 256, 0, stream>>>(x, g0, g1, out);
}